// Round 1
// baseline (10.214 us; speedup 1.0000x reference)
//
#include <hip/hip_runtime.h>

// Haar featurization (10 levels, 1023 features, exactly one ±1 per level)
// fused with MLP 1023->8 (gather) ->8 ->3.
//
// Exactness argument: level-j interval edges are k*2^-j (dyadic, exact in
// f32). t*2^j is an exact f32 scaling; k = floor(t*2^j) identifies the unique
// interval containing t in [0,1); frac = t*2^j - k is exact (Sterbenz);
// sign = frac < 0.5 ? +1 : -1 matches the reference's (t < a+w/2) test.

__global__ __launch_bounds__(256) void haar_mlp_kernel(
    const float* __restrict__ t,
    const float* __restrict__ W1, const float* __restrict__ b1,
    const float* __restrict__ W2, const float* __restrict__ b2,
    const float* __restrict__ W3, const float* __restrict__ b3,
    float* __restrict__ out, int n)
{
    // W1: 1023 rows x 8 floats = 2046 float4 = 32736 B of LDS
    __shared__ float4 w1s[2046];
    #pragma unroll
    for (int u = 0; u < 8; ++u) {
        int idx = (int)threadIdx.x + u * 256;
        if (idx < 2046) w1s[idx] = reinterpret_cast<const float4*>(W1)[idx];
    }
    __syncthreads();

    int i = blockIdx.x * 256 + (int)threadIdx.x;
    if (i >= n) return;

    float tv = t[i];

    float h1[8];
    #pragma unroll
    for (int o = 0; o < 8; ++o) h1[o] = b1[o];

    #pragma unroll
    for (int j = 0; j < 10; ++j) {
        float tj = tv * (float)(1 << j);
        float fl = floorf(tj);
        int k = (int)fl;
        // memory-safety clamp (t is uniform [0,1) so this never triggers)
        int kmax = (1 << j) - 1;
        k = (k < 0) ? 0 : (k > kmax ? kmax : k);
        float sgn = (tj - fl < 0.5f) ? 1.0f : -1.0f;
        int row = (1 << j) - 1 + k;
        float4 lo = w1s[row * 2 + 0];
        float4 hi = w1s[row * 2 + 1];
        h1[0] += sgn * lo.x; h1[1] += sgn * lo.y;
        h1[2] += sgn * lo.z; h1[3] += sgn * lo.w;
        h1[4] += sgn * hi.x; h1[5] += sgn * hi.y;
        h1[6] += sgn * hi.z; h1[7] += sgn * hi.w;
    }
    #pragma unroll
    for (int o = 0; o < 8; ++o) h1[o] = fmaxf(h1[o], 0.0f);

    // h2 = relu(h1 @ W2 + b2), W2 is (8,8) row-major: out[o] += h1[q]*W2[q*8+o]
    float h2[8];
    #pragma unroll
    for (int o = 0; o < 8; ++o) {
        float a = b2[o];
        #pragma unroll
        for (int q = 0; q < 8; ++q) a = fmaf(h1[q], W2[q * 8 + o], a);
        h2[o] = fmaxf(a, 0.0f);
    }

    // out = h2 @ W3 + b3, W3 is (8,3)
    float o0 = b3[0], o1 = b3[1], o2 = b3[2];
    #pragma unroll
    for (int q = 0; q < 8; ++q) {
        o0 = fmaf(h2[q], W3[q * 3 + 0], o0);
        o1 = fmaf(h2[q], W3[q * 3 + 1], o1);
        o2 = fmaf(h2[q], W3[q * 3 + 2], o2);
    }
    out[i * 3 + 0] = o0;
    out[i * 3 + 1] = o1;
    out[i * 3 + 2] = o2;
}

extern "C" void kernel_launch(void* const* d_in, const int* in_sizes, int n_in,
                              void* d_out, int out_size, void* d_ws, size_t ws_size,
                              hipStream_t stream) {
    const float* t  = (const float*)d_in[0];
    const float* W1 = (const float*)d_in[1];
    const float* b1 = (const float*)d_in[2];
    const float* W2 = (const float*)d_in[3];
    const float* b2 = (const float*)d_in[4];
    const float* W3 = (const float*)d_in[5];
    const float* b3 = (const float*)d_in[6];
    float* out = (float*)d_out;

    int n = in_sizes[0];  // B*T = 131072
    int grid = (n + 255) / 256;
    haar_mlp_kernel<<<grid, 256, 0, stream>>>(t, W1, b1, W2, b2, W3, b3, out, n);
}